// Round 15
// baseline (190.065 us; speedup 1.0000x reference)
//
#include <hip/hip_runtime.h>
#include <stdint.h>

typedef __bf16 bf16x8 __attribute__((ext_vector_type(8)));
typedef __bf16 bf16x4v __attribute__((ext_vector_type(4)));
typedef float f32x4 __attribute__((ext_vector_type(4)));

#define TOK 49
#define CDIM 192
#define NHEAD 6
#define THREADS 768
#define QKSCALE 0.17677669529663687f
#define LOG2E 1.4426950408889634f

// LDS (73728 B total -> 2 blocks/CU at 768 threads; 24 waves/CU needs <=85 VGPR -> lean phases):
// X region @0      (24576): ph1-2: x [64][192] bf16 stride 384B swzA
//                           ph3: per-wave scratch [32][32]swzQ (q^T), then P0, then P1 [16][64]swzA
//                           (same wave-private 2K slot, serialized by in-order DS ops)
//                           post-attn: attn_o [64][192] swzA
// K region @24576  (24576): k 6x[64][32] swzQ (never overwritten after ph2a)
// V region @49152  (24576): vT 6x[32][64] stride 128B swzA
// (ones tile eliminated: the row-sum A-fragment is (l15==0)?1:0, built in registers)
#define XOFF   0u
#define KOFF   24576u
#define VOFF   49152u
#define SMEM_BYTES 73728u

__device__ __forceinline__ unsigned short f2bf(float f) {
  unsigned u = __float_as_uint(f);
  return (unsigned short)((u + 0x7fffu + ((u >> 16) & 1u)) >> 16);  // RNE (pack kernel only)
}
// XOR-swizzle byte-in-row for stride%128==0 tiles (bits 4-6)
__device__ __forceinline__ uint32_t swzA(uint32_t row, uint32_t b) { return b ^ ((row & 7u) << 4); }
// XOR-swizzle for stride-64B tiles (bits 4-5)
__device__ __forceinline__ uint32_t swzQ(uint32_t row, uint32_t b) { return b ^ (((row >> 1) & 3u) << 4); }

// Fused pack kernel: wqkv fragments (idx<13824), wproj fragments (next 4608),
// bias_c C-fragment table (last 6144). One launch instead of three.
// Fragment packing: frag (nt, ks): lane l gets W[ks*32 + (l>>4)*8 + j][nt*16 + (l&15)],
// j=0..7, at ((nt*6+ks)*64 + l)*8 bf16. Same lane map serves A- and B-operand roles (gfx950).
// Bias table (transposed C-layout for S^T): out[((head*4+qt)*4+kt)*64+lane][r] =
//   log2e * bias(qrow = qt*16 + (lane&15), kcol = kt*16 + (lane>>4)*4 + r), -1e30 where masked.
__global__ void wa_pack_all(const float* __restrict__ qkv_w, const float* __restrict__ proj_w,
                            const float* __restrict__ rpb,
                            unsigned short* __restrict__ wqkv, unsigned short* __restrict__ wproj,
                            float* __restrict__ bias_c) {
  int idx = blockIdx.x * blockDim.x + threadIdx.x;
  if (idx < 36 * 6 * 64) {
    int l = idx & 63, frag = idx >> 6, ks = frag % 6, nt = frag / 6;
    float sc = (nt < 12) ? (QKSCALE * LOG2E) : 1.0f;   // q cols pre-scaled by D^-0.5 * log2e
    int n = nt * 16 + (l & 15);
    int k0 = ks * 32 + ((l >> 4) << 3);
    unsigned short v[8];
#pragma unroll
    for (int j = 0; j < 8; ++j) v[j] = f2bf(qkv_w[(k0 + j) * 576 + n] * sc);
    ushort4* dst = reinterpret_cast<ushort4*>(wqkv + (size_t)idx * 8);
    dst[0] = make_ushort4(v[0], v[1], v[2], v[3]);
    dst[1] = make_ushort4(v[4], v[5], v[6], v[7]);
  } else if (idx < 36 * 6 * 64 + 12 * 6 * 64) {
    int id = idx - 36 * 6 * 64;
    int l = id & 63, frag = id >> 6, ks = frag % 6, nt = frag / 6;
    int n = nt * 16 + (l & 15);
    int k0 = ks * 32 + ((l >> 4) << 3);
    unsigned short v[8];
#pragma unroll
    for (int j = 0; j < 8; ++j) v[j] = f2bf(proj_w[(k0 + j) * 192 + n]);
    ushort4* dst = reinterpret_cast<ushort4*>(wproj + (size_t)id * 8);
    dst[0] = make_ushort4(v[0], v[1], v[2], v[3]);
    dst[1] = make_ushort4(v[4], v[5], v[6], v[7]);
  } else {
    int id = idx - (36 * 6 * 64 + 12 * 6 * 64);   // < 6144
    int lane = id & 63, kt = (id >> 6) & 3, qt = (id >> 8) & 3, head = id >> 10;
    int qrow = qt * 16 + (lane & 15);
    int kcol0 = kt * 16 + ((lane >> 4) << 2);
    float4 v;
    float* vp = reinterpret_cast<float*>(&v);
#pragma unroll
    for (int r = 0; r < 4; ++r) {
      int kcol = kcol0 + r;
      float val = -1e30f;
      if (qrow < TOK && kcol < TOK) {
        int ri = (qrow / 7 - kcol / 7 + 6) * 13 + (qrow % 7 - kcol % 7 + 6);
        val = rpb[ri * NHEAD + head] * LOG2E;
      }
      vp[r] = val;
    }
    *reinterpret_cast<float4*>(bias_c + (size_t)id * 4) = v;
  }
}

__global__ __launch_bounds__(THREADS, 6) void wa_main(
    const float* __restrict__ x,
    const float* __restrict__ qkv_b,
    const float* __restrict__ proj_b,
    const float* __restrict__ bias_c,          // transposed C-fragment bias table (x log2e)
    const unsigned short* __restrict__ wqkv,   // packed 36 ntiles (q cols pre-scaled)
    const unsigned short* __restrict__ wproj,  // packed 12 ntiles
    float* __restrict__ out) {
  extern __shared__ __align__(16) char smem[];
  const int tid = threadIdx.x;
  const int lane = tid & 63;
  const int wave = __builtin_amdgcn_readfirstlane(tid >> 6);  // wave-uniform -> SGPR (0..11)
  const int l15 = lane & 15;
  const int g16 = (lane >> 4) << 4;   // byte offset of this lane-group's 16B k-slice
  const int rloc0 = (lane >> 4) << 2;
  const int b = blockIdx.x;
  const float* xg = x + (size_t)b * (TOK * CDIM);
  const int h = wave >> 1;            // head for q/attention phases
  const int mbase = (wave & 1) << 1;  // first of 2 owned q m-tiles

  // ---- Phase 1: x -> LDS bf16 [64][192] (rows 49..63 zero) ----
  for (int c = tid; c < 64 * 48; c += THREADS) {
    int r = c / 48;
    int cc = (c % 48) * 4;
    uint32_t addr = XOFF + (uint32_t)r * 384u + swzA((uint32_t)r, (uint32_t)(cc * 2));
    bf16x4v hv;
    if (r < TOK) {
      const float4 v = *reinterpret_cast<const float4*>(xg + r * CDIM + cc);
      hv = (bf16x4v){(__bf16)v.x, (__bf16)v.y, (__bf16)v.z, (__bf16)v.w};
    } else {
      hv = (bf16x4v){(__bf16)0.f, (__bf16)0.f, (__bf16)0.f, (__bf16)0.f};
    }
    *reinterpret_cast<bf16x4v*>(smem + addr) = hv;
  }
  __syncthreads();

  // ---- Phase 2a: k (waves 0-5, swapped k^T) or v (waves 6-11), M-OUTER form:
  // per m-tile, hoist the 6 x-fragments into named regs (read once) and feed BOTH
  // owned ntiles (48 -> 24 LDS b128 A-reads/wave). Accumulators are only accA/accB
  // (8 regs) live across the ks-chain — avoids the r4/r9/r10/r13 spill signature
  // (>=32 acc regs). wf fragments reloaded per m (L2-hot, cheap).
  {
    const bool isv = wave >= 6;
    const int hw = isv ? wave - 6 : wave;          // head written
    const int ntg0 = (isv ? 24 : 12) + 2 * hw;
    // loop-invariant biases
    float bvA_s = 0.f, bvB_s = 0.f;
    float4 bvA4, bvB4;
    if (isv) {
      bvA_s = qkv_b[(ntg0 + 0) * 16 + l15];
      bvB_s = qkv_b[(ntg0 + 1) * 16 + l15];
    } else {
      bvA4 = *reinterpret_cast<const float4*>(qkv_b + (ntg0 + 0) * 16 + rloc0);
      bvB4 = *reinterpret_cast<const float4*>(qkv_b + (ntg0 + 1) * 16 + rloc0);
    }
#pragma unroll
    for (int m = 0; m < 4; ++m) {
      const uint32_t row = (uint32_t)(m * 16 + l15);
      const uint32_t rb = XOFF + row * 384u;
      const bf16x8 xf0 = *reinterpret_cast<const bf16x8*>(smem + rb + swzA(row, (uint32_t)(0 * 64 + g16)));
      const bf16x8 xf1 = *reinterpret_cast<const bf16x8*>(smem + rb + swzA(row, (uint32_t)(1 * 64 + g16)));
      const bf16x8 xf2 = *reinterpret_cast<const bf16x8*>(smem + rb + swzA(row, (uint32_t)(2 * 64 + g16)));
      const bf16x8 xf3 = *reinterpret_cast<const bf16x8*>(smem + rb + swzA(row, (uint32_t)(3 * 64 + g16)));
      const bf16x8 xf4 = *reinterpret_cast<const bf16x8*>(smem + rb + swzA(row, (uint32_t)(4 * 64 + g16)));
      const bf16x8 xf5 = *reinterpret_cast<const bf16x8*>(smem + rb + swzA(row, (uint32_t)(5 * 64 + g16)));
      f32x4 accA, accB;
      if (isv) {
        accA = (f32x4){bvA_s, bvA_s, bvA_s, bvA_s};
        accB = (f32x4){bvB_s, bvB_s, bvB_s, bvB_s};
      } else {
        accA = (f32x4){bvA4.x, bvA4.y, bvA4.z, bvA4.w};
        accB = (f32x4){bvB4.x, bvB4.y, bvB4.z, bvB4.w};
      }
#define P2STEP(KS, XF)                                                                              \
      {                                                                                             \
        bf16x8 wf0 = *reinterpret_cast<const bf16x8*>(wqkv + ((size_t)((ntg0 + 0) * 6 + (KS)) * 64 + lane) * 8); \
        bf16x8 wf1 = *reinterpret_cast<const bf16x8*>(wqkv + ((size_t)((ntg0 + 1) * 6 + (KS)) * 64 + lane) * 8); \
        if (isv) {                                                                                  \
          accA = __builtin_amdgcn_mfma_f32_16x16x32_bf16(XF, wf0, accA, 0, 0, 0);                   \
          accB = __builtin_amdgcn_mfma_f32_16x16x32_bf16(XF, wf1, accB, 0, 0, 0);                   \
        } else {                                                                                    \
          accA = __builtin_amdgcn_mfma_f32_16x16x32_bf16(wf0, XF, accA, 0, 0, 0);                   \
          accB = __builtin_amdgcn_mfma_f32_16x16x32_bf16(wf1, XF, accB, 0, 0, 0);                   \
        }                                                                                           \
      }
      P2STEP(0, xf0) P2STEP(1, xf1) P2STEP(2, xf2) P2STEP(3, xf3) P2STEP(4, xf4) P2STEP(5, xf5)
#undef P2STEP
      if (isv) {
        // vT stores: [d][tok], 4 consecutive tokens -> packed 8B. A: d=l15, B: d=16+l15
        uint32_t c0 = (uint32_t)((m * 16 + rloc0) * 2);
        uint32_t vb0 = VOFF + (uint32_t)hw * 4096u;
        *reinterpret_cast<bf16x4v*>(smem + vb0 + (uint32_t)l15 * 128u + swzA((uint32_t)l15, c0)) =
            (bf16x4v){(__bf16)accA[0], (__bf16)accA[1], (__bf16)accA[2], (__bf16)accA[3]};
        *reinterpret_cast<bf16x4v*>(smem + vb0 + (uint32_t)(16 + l15) * 128u + swzA((uint32_t)(16 + l15), c0)) =
            (bf16x4v){(__bf16)accB[0], (__bf16)accB[1], (__bf16)accB[2], (__bf16)accB[3]};
      } else {
        // k stores: [tok][d], 4 consecutive d -> packed 8B. A: d-base 0, B: d-base 16
        uint32_t kb0 = KOFF + (uint32_t)hw * 4096u + row * 64u;
        *reinterpret_cast<bf16x4v*>(smem + kb0 + swzQ(row, (uint32_t)(rloc0 * 2))) =
            (bf16x4v){(__bf16)accA[0], (__bf16)accA[1], (__bf16)accA[2], (__bf16)accA[3]};
        *reinterpret_cast<bf16x4v*>(smem + kb0 + swzQ(row, (uint32_t)((16 + rloc0) * 2))) =
            (bf16x4v){(__bf16)accB[0], (__bf16)accB[1], (__bf16)accB[2], (__bf16)accB[3]};
      }
    }
  }

  // ---- Phase 2b: q^T for own block (tokens 32*(wave&1)+0..31, ch 32h..32h+31) -> regs ----
  f32x4 qacc[2][2];   // [tok-tile][ch-tile]: rows = ch (n*16+rloc0+r), cols = tok
  {
#pragma unroll
    for (int n = 0; n < 2; ++n) {
      float4 bv4 = *reinterpret_cast<const float4*>(qkv_b + (2 * h + n) * 16 + rloc0);
      const float sc = QKSCALE * LOG2E;
      f32x4 bi = (f32x4){bv4.x * sc, bv4.y * sc, bv4.z * sc, bv4.w * sc};
      qacc[0][n] = bi;
      qacc[1][n] = bi;
    }
#pragma unroll
    for (int ks = 0; ks < 6; ++ks) {
      bf16x8 wf[2];
#pragma unroll
      for (int n = 0; n < 2; ++n)
        wf[n] = *reinterpret_cast<const bf16x8*>(wqkv + ((size_t)((2 * h + n) * 6 + ks) * 64 + lane) * 8);
#pragma unroll
      for (int tt = 0; tt < 2; ++tt) {
        uint32_t row = (uint32_t)((mbase + tt) * 16 + l15);
        bf16x8 xf = *reinterpret_cast<const bf16x8*>(smem + XOFF + row * 384u + swzA(row, (uint32_t)(ks * 64 + g16)));
#pragma unroll
        for (int n = 0; n < 2; ++n)
          qacc[tt][n] = __builtin_amdgcn_mfma_f32_16x16x32_bf16(wf[n], xf, qacc[tt][n], 0, 0, 0);
      }
    }
  }
  __syncthreads();   // x reads + k/v writes retire; x region becomes per-wave scratch

  const uint32_t sb = XOFF + (uint32_t)wave * 2048u;   // wave-private scratch
  const uint32_t vbase = VOFF + (uint32_t)h * 4096u;
  const uint32_t kbase = KOFF + (uint32_t)h * 4096u;

  // ones A-fragment in registers: row-sum matrix row0=1, so lane fragment = (l15==0)?1:0
  const __bf16 onev = (l15 == 0) ? (__bf16)1.0f : (__bf16)0.0f;
  const bf16x8 obf = (bf16x8){onev, onev, onev, onev, onev, onev, onev, onev};

  // ---- t0 bias loads issued early: L2 latency hides under the q scratch round-trip ----
  f32x4 s[4];
  {
    const float* bt = bias_c + (size_t)((h * 4 + mbase) * 4 * 64 + lane) * 4;
#pragma unroll
    for (int nt = 0; nt < 4; ++nt)
      s[nt] = *reinterpret_cast<const f32x4*>(bt + (size_t)nt * 256);
  }

  // ---- q scatter: packed 8B stores into scratch [32 tok][32 ch] swzQ, then row reads ----
  bf16x8 qa0, qa1;
  {
#pragma unroll
    for (int tt = 0; tt < 2; ++tt)
#pragma unroll
      for (int n = 0; n < 2; ++n) {
        uint32_t row = (uint32_t)(tt * 16 + l15);
        uint32_t cb = (uint32_t)((n * 16 + rloc0) * 2);
        bf16x4v hv = (bf16x4v){(__bf16)qacc[tt][n][0], (__bf16)qacc[tt][n][1],
                               (__bf16)qacc[tt][n][2], (__bf16)qacc[tt][n][3]};
        *reinterpret_cast<bf16x4v*>(smem + sb + row * 64u + swzQ(row, cb)) = hv;
      }
    asm volatile("s_waitcnt lgkmcnt(0)" ::: "memory");
    qa0 = *reinterpret_cast<const bf16x8*>(smem + sb + (uint32_t)l15 * 64u + swzQ((uint32_t)l15, (uint32_t)g16));
    uint32_t r1 = (uint32_t)(l15 + 16);
    qa1 = *reinterpret_cast<const bf16x8*>(smem + sb + r1 * 64u + swzQ(r1, (uint32_t)g16));
  }

  bf16x4v p0[2];  // normalized t0 output (packed), held until attn_o writes

  // ---- t0: S^T = mfma(K, Q^T) -> exp2 -> P0 (own scratch, packed) -> o^T = mfma(V^T, P^T) ----
  {
#pragma unroll
    for (int nt = 0; nt < 4; ++nt) {
      uint32_t krow = (uint32_t)(nt * 16 + l15);
      bf16x8 kb = *reinterpret_cast<const bf16x8*>(smem + kbase + krow * 64u + swzQ(krow, (uint32_t)g16));
      s[nt] = __builtin_amdgcn_mfma_f32_16x16x32_bf16(kb, qa0, s[nt], 0, 0, 0);
    }
    // P0 = exp2(S^T): thread holds fixed qt=l15, 4 consecutive kt -> packed row store.
    // DS ops are in-order per wave, so these stores cannot bypass the qa reads above.
#pragma unroll
    for (int nt = 0; nt < 4; ++nt) {
      bf16x4v hv = (bf16x4v){(__bf16)exp2f(s[nt][0]), (__bf16)exp2f(s[nt][1]),
                             (__bf16)exp2f(s[nt][2]), (__bf16)exp2f(s[nt][3])};
      uint32_t cb = (uint32_t)((nt * 16 + rloc0) * 2);
      *reinterpret_cast<bf16x4v*>(smem + sb + (uint32_t)l15 * 128u + swzA((uint32_t)l15, cb)) = hv;
    }
    asm volatile("s_waitcnt lgkmcnt(0)" ::: "memory");
    f32x4 o[2], o2;
    o[0] = (f32x4){0.f, 0.f, 0.f, 0.f};
    o[1] = (f32x4){0.f, 0.f, 0.f, 0.f};
    o2 = (f32x4){0.f, 0.f, 0.f, 0.f};
#pragma unroll
    for (int ks = 0; ks < 2; ++ks) {
      bf16x8 pa = *reinterpret_cast<const bf16x8*>(smem + sb + (uint32_t)l15 * 128u + swzA((uint32_t)l15, (uint32_t)(ks * 64 + g16)));
#pragma unroll
      for (int n2 = 0; n2 < 2; ++n2) {
        uint32_t vrow = (uint32_t)(n2 * 16 + l15);
        bf16x8 vb = *reinterpret_cast<const bf16x8*>(smem + vbase + vrow * 128u + swzA(vrow, (uint32_t)(ks * 64 + g16)));
        o[n2] = __builtin_amdgcn_mfma_f32_16x16x32_bf16(vb, pa, o[n2], 0, 0, 0);
      }
      o2 = __builtin_amdgcn_mfma_f32_16x16x32_bf16(obf, pa, o2, 0, 0, 0);
    }
    // row-sum for qt=l15 lives in o2[0] of lane l15 (grp 0)
    float is = __builtin_amdgcn_rcpf(__shfl(o2[0], l15));
#pragma unroll
    for (int n2 = 0; n2 < 2; ++n2)
      p0[n2] = (bf16x4v){(__bf16)(o[n2][0] * is), (__bf16)(o[n2][1] * is),
                         (__bf16)(o[n2][2] * is), (__bf16)(o[n2][3] * is)};
  }

  // ---- t1: fully after t0, no block-wide barrier in between. k region is never
  // overwritten, and P1 reuses the wave-private scratch slot (P0 dead after t0's PV
  // reads; per-wave in-order DS ops serialize the slot reuse). ----
  bf16x4v p1[2];
  {
    f32x4 s1[4];
    const float* bt = bias_c + (size_t)((h * 4 + mbase + 1) * 4 * 64 + lane) * 4;
#pragma unroll
    for (int nt = 0; nt < 4; ++nt)
      s1[nt] = *reinterpret_cast<const f32x4*>(bt + (size_t)nt * 256);
#pragma unroll
    for (int nt = 0; nt < 4; ++nt) {
      uint32_t krow = (uint32_t)(nt * 16 + l15);
      bf16x8 kb = *reinterpret_cast<const bf16x8*>(smem + kbase + krow * 64u + swzQ(krow, (uint32_t)g16));
      s1[nt] = __builtin_amdgcn_mfma_f32_16x16x32_bf16(kb, qa1, s1[nt], 0, 0, 0);
    }
#pragma unroll
    for (int nt = 0; nt < 4; ++nt) {
      bf16x4v hv = (bf16x4v){(__bf16)exp2f(s1[nt][0]), (__bf16)exp2f(s1[nt][1]),
                             (__bf16)exp2f(s1[nt][2]), (__bf16)exp2f(s1[nt][3])};
      uint32_t cb = (uint32_t)((nt * 16 + rloc0) * 2);
      *reinterpret_cast<bf16x4v*>(smem + sb + (uint32_t)l15 * 128u + swzA((uint32_t)l15, cb)) = hv;
    }
    asm volatile("s_waitcnt lgkmcnt(0)" ::: "memory");
    f32x4 o[2], o2;
    o[0] = (f32x4){0.f, 0.f, 0.f, 0.f};
    o[1] = (f32x4){0.f, 0.f, 0.f, 0.f};
    o2 = (f32x4){0.f, 0.f, 0.f, 0.f};
#pragma unroll
    for (int ks = 0; ks < 2; ++ks) {
      bf16x8 pa = *reinterpret_cast<const bf16x8*>(smem + sb + (uint32_t)l15 * 128u + swzA((uint32_t)l15, (uint32_t)(ks * 64 + g16)));
#pragma unroll
      for (int n2 = 0; n2 < 2; ++n2) {
        uint32_t vrow = (uint32_t)(n2 * 16 + l15);
        bf16x8 vb = *reinterpret_cast<const bf16x8*>(smem + vbase + vrow * 128u + swzA(vrow, (uint32_t)(ks * 64 + g16)));
        o[n2] = __builtin_amdgcn_mfma_f32_16x16x32_bf16(vb, pa, o[n2], 0, 0, 0);
      }
      o2 = __builtin_amdgcn_mfma_f32_16x16x32_bf16(obf, pa, o2, 0, 0, 0);
    }
    float is = __builtin_amdgcn_rcpf(__shfl(o2[0], l15));
#pragma unroll
    for (int n2 = 0; n2 < 2; ++n2)
      p1[n2] = (bf16x4v){(__bf16)(o[n2][0] * is), (__bf16)(o[n2][1] * is),
                         (__bf16)(o[n2][2] * is), (__bf16)(o[n2][3] * is)};
  }
  __syncthreads();   // all waves' scratch/k/v reads retire; X region -> attn_o

  // ---- attn_o writes for both tiles: o^T layout -> packed 8B row stores ----
  {
    uint32_t row0 = (uint32_t)(mbase * 16 + l15);
    uint32_t row1 = row0 + 16u;
#pragma unroll
    for (int n2 = 0; n2 < 2; ++n2) {
      uint32_t cb = (uint32_t)((h * 32 + n2 * 16 + rloc0) * 2);
      *reinterpret_cast<bf16x4v*>(smem + XOFF + row0 * 384u + swzA(row0, cb)) = p0[n2];
      *reinterpret_cast<bf16x4v*>(smem + XOFF + row1 * 384u + swzA(row1, cb)) = p1[n2];
    }
  }
  __syncthreads();

  // ---- Phase 4: proj, 2x2-tiled with NAMED accumulators (all prior state dead here).
  // wave -> mtile-pair (wave&1), ntile-pair (wave>>1); each A read feeds 2 MFMAs.
  {
    const int mp = wave & 1;
    const int np = wave >> 1;
    const float pb0 = proj_b[(2 * np + 0) * 16 + l15];
    const float pb1 = proj_b[(2 * np + 1) * 16 + l15];
    f32x4 po00 = (f32x4){pb0, pb0, pb0, pb0};
    f32x4 po01 = (f32x4){pb1, pb1, pb1, pb1};
    f32x4 po10 = po00;
    f32x4 po11 = po01;
#pragma unroll
    for (int ks = 0; ks < 6; ++ks) {
      bf16x8 bp0 = *reinterpret_cast<const bf16x8*>(wproj + ((size_t)((2 * np + 0) * 6 + ks) * 64 + lane) * 8);
      bf16x8 bp1 = *reinterpret_cast<const bf16x8*>(wproj + ((size_t)((2 * np + 1) * 6 + ks) * 64 + lane) * 8);
      uint32_t rowa = (uint32_t)((2 * mp + 0) * 16 + l15);
      bf16x8 a0 = *reinterpret_cast<const bf16x8*>(smem + XOFF + rowa * 384u + swzA(rowa, (uint32_t)(ks * 64 + g16)));
      po00 = __builtin_amdgcn_mfma_f32_16x16x32_bf16(a0, bp0, po00, 0, 0, 0);
      po01 = __builtin_amdgcn_mfma_f32_16x16x32_bf16(a0, bp1, po01, 0, 0, 0);
      uint32_t rowb = rowa + 16u;
      bf16x8 a1 = *reinterpret_cast<const bf16x8*>(smem + XOFF + rowb * 384u + swzA(rowb, (uint32_t)(ks * 64 + g16)));
      po10 = __builtin_amdgcn_mfma_f32_16x16x32_bf16(a1, bp0, po10, 0, 0, 0);
      po11 = __builtin_amdgcn_mfma_f32_16x16x32_bf16(a1, bp1, po11, 0, 0, 0);
    }
    float* outg = out + (size_t)b * (TOK * CDIM);
    const int col0 = (2 * np + 0) * 16 + l15;
    const int col1 = (2 * np + 1) * 16 + l15;
    const int rA = (2 * mp + 0) * 16 + rloc0;
    const int rB = (2 * mp + 1) * 16 + rloc0;
#pragma unroll
    for (int r = 0; r < 4; ++r) {
      int rowA = rA + r;
      if (rowA < TOK) {
        outg[rowA * CDIM + col0] = po00[r];
        outg[rowA * CDIM + col1] = po01[r];
      }
      int rowB = rB + r;
      if (rowB < TOK) {
        outg[rowB * CDIM + col0] = po10[r];
        outg[rowB * CDIM + col1] = po11[r];
      }
    }
  }
}

extern "C" void kernel_launch(void* const* d_in, const int* in_sizes, int n_in,
                              void* d_out, int out_size, void* d_ws, size_t ws_size,
                              hipStream_t stream) {
  const float* x = (const float*)d_in[0];
  // d_in[1] = q_global : unused by the reference
  const float* qkv_w = (const float*)d_in[2];
  const float* qkv_b = (const float*)d_in[3];
  const float* proj_w = (const float*)d_in[4];
  const float* proj_b = (const float*)d_in[5];
  const float* rpb = (const float*)d_in[6];

  unsigned short* wqkv = (unsigned short*)d_ws;                 // 36*6*64*8 bf16 = 221184 B
  unsigned short* wproj = wqkv + (size_t)36 * 6 * 64 * 8;       // 12*6*64*8 bf16 = 73728 B
  float* bias_c = (float*)(wproj + (size_t)12 * 6 * 64 * 8);    // 6*4*4*64*4 f32 = 98304 B

  // fused pack: 13824 (wqkv) + 4608 (wproj) + 6144 (bias) = 24576 threads = 96 blocks
  wa_pack_all<<<96, 256, 0, stream>>>(qkv_w, proj_w, rpb, wqkv, wproj, bias_c);

  hipFuncSetAttribute((const void*)wa_main, hipFuncAttributeMaxDynamicSharedMemorySize, (int)SMEM_BYTES);
  wa_main<<<2048, THREADS, SMEM_BYTES, stream>>>(x, qkv_b, proj_b, bias_c, wqkv, wproj, (float*)d_out);
}

// Round 16
// 74.026 us; speedup vs baseline: 2.5676x; 2.5676x over previous
//
#include <hip/hip_runtime.h>
#include <stdint.h>

typedef __bf16 bf16x8 __attribute__((ext_vector_type(8)));
typedef __bf16 bf16x4v __attribute__((ext_vector_type(4)));
typedef float f32x4 __attribute__((ext_vector_type(4)));

#define TOK 49
#define CDIM 192
#define NHEAD 6
#define THREADS 768
#define QKSCALE 0.17677669529663687f
#define LOG2E 1.4426950408889634f

// LDS (73728 B total -> 2 blocks/CU at 768 threads; 24 waves/CU needs <=85 VGPR -> lean phases):
// X region @0      (24576): ph1-2: x [64][192] bf16 stride 384B swzA
//                           ph3: per-wave scratch [32][32]swzQ (q^T), then P0, then P1 [16][64]swzA
//                           (same wave-private 2K slot, serialized by in-order DS ops)
//                           post-attn: attn_o [64][192] swzA
// K region @24576  (24576): k 6x[64][32] swzQ (never overwritten after ph2a)
// V region @49152  (24576): vT 6x[32][64] stride 128B swzA
// (ones tile eliminated: the row-sum A-fragment is (l15==0)?1:0, built in registers)
#define XOFF   0u
#define KOFF   24576u
#define VOFF   49152u
#define SMEM_BYTES 73728u

__device__ __forceinline__ unsigned short f2bf(float f) {
  unsigned u = __float_as_uint(f);
  return (unsigned short)((u + 0x7fffu + ((u >> 16) & 1u)) >> 16);  // RNE (pack kernel only)
}
// XOR-swizzle byte-in-row for stride%128==0 tiles (bits 4-6)
__device__ __forceinline__ uint32_t swzA(uint32_t row, uint32_t b) { return b ^ ((row & 7u) << 4); }
// XOR-swizzle for stride-64B tiles (bits 4-5)
__device__ __forceinline__ uint32_t swzQ(uint32_t row, uint32_t b) { return b ^ (((row >> 1) & 3u) << 4); }

// Fused pack kernel: wqkv fragments (idx<13824), wproj fragments (next 4608),
// bias_c C-fragment table (last 6144). One launch instead of three.
// Fragment packing: frag (nt, ks): lane l gets W[ks*32 + (l>>4)*8 + j][nt*16 + (l&15)],
// j=0..7, at ((nt*6+ks)*64 + l)*8 bf16. Same lane map serves A- and B-operand roles (gfx950).
// Bias table (transposed C-layout for S^T): out[((head*4+qt)*4+kt)*64+lane][r] =
//   log2e * bias(qrow = qt*16 + (lane&15), kcol = kt*16 + (lane>>4)*4 + r), -1e30 where masked.
__global__ void wa_pack_all(const float* __restrict__ qkv_w, const float* __restrict__ proj_w,
                            const float* __restrict__ rpb,
                            unsigned short* __restrict__ wqkv, unsigned short* __restrict__ wproj,
                            float* __restrict__ bias_c) {
  int idx = blockIdx.x * blockDim.x + threadIdx.x;
  if (idx < 36 * 6 * 64) {
    int l = idx & 63, frag = idx >> 6, ks = frag % 6, nt = frag / 6;
    float sc = (nt < 12) ? (QKSCALE * LOG2E) : 1.0f;   // q cols pre-scaled by D^-0.5 * log2e
    int n = nt * 16 + (l & 15);
    int k0 = ks * 32 + ((l >> 4) << 3);
    unsigned short v[8];
#pragma unroll
    for (int j = 0; j < 8; ++j) v[j] = f2bf(qkv_w[(k0 + j) * 576 + n] * sc);
    ushort4* dst = reinterpret_cast<ushort4*>(wqkv + (size_t)idx * 8);
    dst[0] = make_ushort4(v[0], v[1], v[2], v[3]);
    dst[1] = make_ushort4(v[4], v[5], v[6], v[7]);
  } else if (idx < 36 * 6 * 64 + 12 * 6 * 64) {
    int id = idx - 36 * 6 * 64;
    int l = id & 63, frag = id >> 6, ks = frag % 6, nt = frag / 6;
    int n = nt * 16 + (l & 15);
    int k0 = ks * 32 + ((l >> 4) << 3);
    unsigned short v[8];
#pragma unroll
    for (int j = 0; j < 8; ++j) v[j] = f2bf(proj_w[(k0 + j) * 192 + n]);
    ushort4* dst = reinterpret_cast<ushort4*>(wproj + (size_t)id * 8);
    dst[0] = make_ushort4(v[0], v[1], v[2], v[3]);
    dst[1] = make_ushort4(v[4], v[5], v[6], v[7]);
  } else {
    int id = idx - (36 * 6 * 64 + 12 * 6 * 64);   // < 6144
    int lane = id & 63, kt = (id >> 6) & 3, qt = (id >> 8) & 3, head = id >> 10;
    int qrow = qt * 16 + (lane & 15);
    int kcol0 = kt * 16 + ((lane >> 4) << 2);
    float4 v;
    float* vp = reinterpret_cast<float*>(&v);
#pragma unroll
    for (int r = 0; r < 4; ++r) {
      int kcol = kcol0 + r;
      float val = -1e30f;
      if (qrow < TOK && kcol < TOK) {
        int ri = (qrow / 7 - kcol / 7 + 6) * 13 + (qrow % 7 - kcol % 7 + 6);
        val = rpb[ri * NHEAD + head] * LOG2E;
      }
      vp[r] = val;
    }
    *reinterpret_cast<float4*>(bias_c + (size_t)id * 4) = v;
  }
}

__global__ __launch_bounds__(THREADS, 6) void wa_main(
    const float* __restrict__ x,
    const float* __restrict__ qkv_b,
    const float* __restrict__ proj_b,
    const float* __restrict__ bias_c,          // transposed C-fragment bias table (x log2e)
    const unsigned short* __restrict__ wqkv,   // packed 36 ntiles (q cols pre-scaled)
    const unsigned short* __restrict__ wproj,  // packed 12 ntiles
    float* __restrict__ out) {
  extern __shared__ __align__(16) char smem[];
  const int tid = threadIdx.x;
  const int lane = tid & 63;
  const int wave = __builtin_amdgcn_readfirstlane(tid >> 6);  // wave-uniform -> SGPR (0..11)
  const int l15 = lane & 15;
  const int g16 = (lane >> 4) << 4;   // byte offset of this lane-group's 16B k-slice
  const int rloc0 = (lane >> 4) << 2;
  const int b = blockIdx.x;
  const float* xg = x + (size_t)b * (TOK * CDIM);
  const int h = wave >> 1;            // head for q/attention phases
  const int mbase = (wave & 1) << 1;  // first of 2 owned q m-tiles

  // ---- Phase 1: x -> LDS bf16 [64][192] (rows 49..63 zero) ----
  for (int c = tid; c < 64 * 48; c += THREADS) {
    int r = c / 48;
    int cc = (c % 48) * 4;
    uint32_t addr = XOFF + (uint32_t)r * 384u + swzA((uint32_t)r, (uint32_t)(cc * 2));
    bf16x4v hv;
    if (r < TOK) {
      const float4 v = *reinterpret_cast<const float4*>(xg + r * CDIM + cc);
      hv = (bf16x4v){(__bf16)v.x, (__bf16)v.y, (__bf16)v.z, (__bf16)v.w};
    } else {
      hv = (bf16x4v){(__bf16)0.f, (__bf16)0.f, (__bf16)0.f, (__bf16)0.f};
    }
    *reinterpret_cast<bf16x4v*>(smem + addr) = hv;
  }
  __syncthreads();

  // ---- Phase 2a: k (waves 0-5, swapped k^T -> packed stores) or v (waves 6-11).
  // Sequential per ntile (acc[4] = 16 regs live): the ONLY spill-free form
  // (r4/r5/r9/r10/r13/r15 lessons — any wider reuse form spills at the 85-VGPR cap).
  {
    const bool isv = wave >= 6;
    const int hw = isv ? wave - 6 : wave;          // head written
    if (isv) {
      const int ntg0 = 24 + 2 * hw;
#pragma unroll
      for (int i = 0; i < 2; ++i) {
        const int nt = ntg0 + i;
        const float bv = qkv_b[nt * 16 + l15];
        f32x4 acc[4];
#pragma unroll
        for (int m = 0; m < 4; ++m) acc[m] = (f32x4){bv, bv, bv, bv};
#pragma unroll
        for (int ks = 0; ks < 6; ++ks) {
          bf16x8 bf = *reinterpret_cast<const bf16x8*>(wqkv + ((size_t)(nt * 6 + ks) * 64 + lane) * 8);
#pragma unroll
          for (int m = 0; m < 4; ++m) {
            uint32_t row = (uint32_t)(m * 16 + l15);
            bf16x8 a = *reinterpret_cast<const bf16x8*>(smem + XOFF + row * 384u + swzA(row, (uint32_t)(ks * 64 + g16)));
            acc[m] = __builtin_amdgcn_mfma_f32_16x16x32_bf16(a, bf, acc[m], 0, 0, 0);
          }
        }
        const int d = (i << 4) + l15;
        uint32_t rowbase = VOFF + (uint32_t)hw * 4096u + (uint32_t)d * 128u;
#pragma unroll
        for (int m = 0; m < 4; ++m) {
          uint32_t c0 = (uint32_t)((m * 16 + rloc0) * 2);
          bf16x4v hv = (bf16x4v){(__bf16)acc[m][0], (__bf16)acc[m][1],
                                 (__bf16)acc[m][2], (__bf16)acc[m][3]};
          *reinterpret_cast<bf16x4v*>(smem + rowbase + swzA((uint32_t)d, c0)) = hv;
        }
      }
    } else {
      const int ntg0 = 12 + 2 * hw;
#pragma unroll
      for (int i = 0; i < 2; ++i) {
        const int nt = ntg0 + i;
        const float4 bv4 = *reinterpret_cast<const float4*>(qkv_b + nt * 16 + rloc0);
        f32x4 acc[4];   // k^T tiles: rows = d (i*16+rloc0+r), cols = tokens (m*16+l15)
#pragma unroll
        for (int m = 0; m < 4; ++m) acc[m] = (f32x4){bv4.x, bv4.y, bv4.z, bv4.w};
#pragma unroll
        for (int ks = 0; ks < 6; ++ks) {
          bf16x8 wf = *reinterpret_cast<const bf16x8*>(wqkv + ((size_t)(nt * 6 + ks) * 64 + lane) * 8);
#pragma unroll
          for (int m = 0; m < 4; ++m) {
            uint32_t row = (uint32_t)(m * 16 + l15);
            bf16x8 xf = *reinterpret_cast<const bf16x8*>(smem + XOFF + row * 384u + swzA(row, (uint32_t)(ks * 64 + g16)));
            acc[m] = __builtin_amdgcn_mfma_f32_16x16x32_bf16(wf, xf, acc[m], 0, 0, 0);
          }
        }
        // store k[tok][d]: row = tok (m*16+l15), 4 consecutive d -> packed 8B
        uint32_t cb = (uint32_t)((i * 16 + rloc0) * 2);
#pragma unroll
        for (int m = 0; m < 4; ++m) {
          uint32_t row = (uint32_t)(m * 16 + l15);
          bf16x4v hv = (bf16x4v){(__bf16)acc[m][0], (__bf16)acc[m][1],
                                 (__bf16)acc[m][2], (__bf16)acc[m][3]};
          *reinterpret_cast<bf16x4v*>(smem + KOFF + (uint32_t)hw * 4096u + row * 64u + swzQ(row, cb)) = hv;
        }
      }
    }
  }

  // ---- Phase 2b: q^T for own block (tokens 32*(wave&1)+0..31, ch 32h..32h+31) -> regs ----
  f32x4 qacc[2][2];   // [tok-tile][ch-tile]: rows = ch (n*16+rloc0+r), cols = tok
  {
#pragma unroll
    for (int n = 0; n < 2; ++n) {
      float4 bv4 = *reinterpret_cast<const float4*>(qkv_b + (2 * h + n) * 16 + rloc0);
      const float sc = QKSCALE * LOG2E;
      f32x4 bi = (f32x4){bv4.x * sc, bv4.y * sc, bv4.z * sc, bv4.w * sc};
      qacc[0][n] = bi;
      qacc[1][n] = bi;
    }
#pragma unroll
    for (int ks = 0; ks < 6; ++ks) {
      bf16x8 wf[2];
#pragma unroll
      for (int n = 0; n < 2; ++n)
        wf[n] = *reinterpret_cast<const bf16x8*>(wqkv + ((size_t)((2 * h + n) * 6 + ks) * 64 + lane) * 8);
#pragma unroll
      for (int tt = 0; tt < 2; ++tt) {
        uint32_t row = (uint32_t)((mbase + tt) * 16 + l15);
        bf16x8 xf = *reinterpret_cast<const bf16x8*>(smem + XOFF + row * 384u + swzA(row, (uint32_t)(ks * 64 + g16)));
#pragma unroll
        for (int n = 0; n < 2; ++n)
          qacc[tt][n] = __builtin_amdgcn_mfma_f32_16x16x32_bf16(wf[n], xf, qacc[tt][n], 0, 0, 0);
      }
    }
  }
  __syncthreads();   // x reads + k/v writes retire; x region becomes per-wave scratch

  const uint32_t sb = XOFF + (uint32_t)wave * 2048u;   // wave-private scratch
  const uint32_t vbase = VOFF + (uint32_t)h * 4096u;
  const uint32_t kbase = KOFF + (uint32_t)h * 4096u;

  // ones A-fragment in registers: row-sum matrix row0=1, so lane fragment = (l15==0)?1:0
  const __bf16 onev = (l15 == 0) ? (__bf16)1.0f : (__bf16)0.0f;
  const bf16x8 obf = (bf16x8){onev, onev, onev, onev, onev, onev, onev, onev};

  // ---- t0 bias loads issued early: L2 latency hides under the q scratch round-trip ----
  f32x4 s[4];
  {
    const float* bt = bias_c + (size_t)((h * 4 + mbase) * 4 * 64 + lane) * 4;
#pragma unroll
    for (int nt = 0; nt < 4; ++nt)
      s[nt] = *reinterpret_cast<const f32x4*>(bt + (size_t)nt * 256);
  }

  // ---- q scatter: packed 8B stores into scratch [32 tok][32 ch] swzQ, then row reads ----
  bf16x8 qa0, qa1;
  {
#pragma unroll
    for (int tt = 0; tt < 2; ++tt)
#pragma unroll
      for (int n = 0; n < 2; ++n) {
        uint32_t row = (uint32_t)(tt * 16 + l15);
        uint32_t cb = (uint32_t)((n * 16 + rloc0) * 2);
        bf16x4v hv = (bf16x4v){(__bf16)qacc[tt][n][0], (__bf16)qacc[tt][n][1],
                               (__bf16)qacc[tt][n][2], (__bf16)qacc[tt][n][3]};
        *reinterpret_cast<bf16x4v*>(smem + sb + row * 64u + swzQ(row, cb)) = hv;
      }
    asm volatile("s_waitcnt lgkmcnt(0)" ::: "memory");
    qa0 = *reinterpret_cast<const bf16x8*>(smem + sb + (uint32_t)l15 * 64u + swzQ((uint32_t)l15, (uint32_t)g16));
    uint32_t r1 = (uint32_t)(l15 + 16);
    qa1 = *reinterpret_cast<const bf16x8*>(smem + sb + r1 * 64u + swzQ(r1, (uint32_t)g16));
  }

  bf16x4v p0[2];  // normalized t0 output (packed), held until attn_o writes

  // ---- t0: S^T = mfma(K, Q^T) -> exp2 -> P0 (own scratch, packed) -> o^T = mfma(V^T, P^T) ----
  {
#pragma unroll
    for (int nt = 0; nt < 4; ++nt) {
      uint32_t krow = (uint32_t)(nt * 16 + l15);
      bf16x8 kb = *reinterpret_cast<const bf16x8*>(smem + kbase + krow * 64u + swzQ(krow, (uint32_t)g16));
      s[nt] = __builtin_amdgcn_mfma_f32_16x16x32_bf16(kb, qa0, s[nt], 0, 0, 0);
    }
    // P0 = exp2(S^T): thread holds fixed qt=l15, 4 consecutive kt -> packed row store.
    // DS ops are in-order per wave, so these stores cannot bypass the qa reads above.
#pragma unroll
    for (int nt = 0; nt < 4; ++nt) {
      bf16x4v hv = (bf16x4v){(__bf16)exp2f(s[nt][0]), (__bf16)exp2f(s[nt][1]),
                             (__bf16)exp2f(s[nt][2]), (__bf16)exp2f(s[nt][3])};
      uint32_t cb = (uint32_t)((nt * 16 + rloc0) * 2);
      *reinterpret_cast<bf16x4v*>(smem + sb + (uint32_t)l15 * 128u + swzA((uint32_t)l15, cb)) = hv;
    }
    asm volatile("s_waitcnt lgkmcnt(0)" ::: "memory");
    f32x4 o[2], o2;
    o[0] = (f32x4){0.f, 0.f, 0.f, 0.f};
    o[1] = (f32x4){0.f, 0.f, 0.f, 0.f};
    o2 = (f32x4){0.f, 0.f, 0.f, 0.f};
#pragma unroll
    for (int ks = 0; ks < 2; ++ks) {
      bf16x8 pa = *reinterpret_cast<const bf16x8*>(smem + sb + (uint32_t)l15 * 128u + swzA((uint32_t)l15, (uint32_t)(ks * 64 + g16)));
#pragma unroll
      for (int n2 = 0; n2 < 2; ++n2) {
        uint32_t vrow = (uint32_t)(n2 * 16 + l15);
        bf16x8 vb = *reinterpret_cast<const bf16x8*>(smem + vbase + vrow * 128u + swzA(vrow, (uint32_t)(ks * 64 + g16)));
        o[n2] = __builtin_amdgcn_mfma_f32_16x16x32_bf16(vb, pa, o[n2], 0, 0, 0);
      }
      o2 = __builtin_amdgcn_mfma_f32_16x16x32_bf16(obf, pa, o2, 0, 0, 0);
    }
    // row-sum for qt=l15 lives in o2[0] of lane l15 (grp 0)
    float is = __builtin_amdgcn_rcpf(__shfl(o2[0], l15));
#pragma unroll
    for (int n2 = 0; n2 < 2; ++n2)
      p0[n2] = (bf16x4v){(__bf16)(o[n2][0] * is), (__bf16)(o[n2][1] * is),
                         (__bf16)(o[n2][2] * is), (__bf16)(o[n2][3] * is)};
  }

  // ---- t1: fully after t0, no block-wide barrier in between. k region is never
  // overwritten, and P1 reuses the wave-private scratch slot (P0 dead after t0's PV
  // reads; per-wave in-order DS ops serialize the slot reuse). ----
  bf16x4v p1[2];
  {
    f32x4 s1[4];
    const float* bt = bias_c + (size_t)((h * 4 + mbase + 1) * 4 * 64 + lane) * 4;
#pragma unroll
    for (int nt = 0; nt < 4; ++nt)
      s1[nt] = *reinterpret_cast<const f32x4*>(bt + (size_t)nt * 256);
#pragma unroll
    for (int nt = 0; nt < 4; ++nt) {
      uint32_t krow = (uint32_t)(nt * 16 + l15);
      bf16x8 kb = *reinterpret_cast<const bf16x8*>(smem + kbase + krow * 64u + swzQ(krow, (uint32_t)g16));
      s1[nt] = __builtin_amdgcn_mfma_f32_16x16x32_bf16(kb, qa1, s1[nt], 0, 0, 0);
    }
#pragma unroll
    for (int nt = 0; nt < 4; ++nt) {
      bf16x4v hv = (bf16x4v){(__bf16)exp2f(s1[nt][0]), (__bf16)exp2f(s1[nt][1]),
                             (__bf16)exp2f(s1[nt][2]), (__bf16)exp2f(s1[nt][3])};
      uint32_t cb = (uint32_t)((nt * 16 + rloc0) * 2);
      *reinterpret_cast<bf16x4v*>(smem + sb + (uint32_t)l15 * 128u + swzA((uint32_t)l15, cb)) = hv;
    }
    asm volatile("s_waitcnt lgkmcnt(0)" ::: "memory");
    f32x4 o[2], o2;
    o[0] = (f32x4){0.f, 0.f, 0.f, 0.f};
    o[1] = (f32x4){0.f, 0.f, 0.f, 0.f};
    o2 = (f32x4){0.f, 0.f, 0.f, 0.f};
#pragma unroll
    for (int ks = 0; ks < 2; ++ks) {
      bf16x8 pa = *reinterpret_cast<const bf16x8*>(smem + sb + (uint32_t)l15 * 128u + swzA((uint32_t)l15, (uint32_t)(ks * 64 + g16)));
#pragma unroll
      for (int n2 = 0; n2 < 2; ++n2) {
        uint32_t vrow = (uint32_t)(n2 * 16 + l15);
        bf16x8 vb = *reinterpret_cast<const bf16x8*>(smem + vbase + vrow * 128u + swzA(vrow, (uint32_t)(ks * 64 + g16)));
        o[n2] = __builtin_amdgcn_mfma_f32_16x16x32_bf16(vb, pa, o[n2], 0, 0, 0);
      }
      o2 = __builtin_amdgcn_mfma_f32_16x16x32_bf16(obf, pa, o2, 0, 0, 0);
    }
    float is = __builtin_amdgcn_rcpf(__shfl(o2[0], l15));
#pragma unroll
    for (int n2 = 0; n2 < 2; ++n2)
      p1[n2] = (bf16x4v){(__bf16)(o[n2][0] * is), (__bf16)(o[n2][1] * is),
                         (__bf16)(o[n2][2] * is), (__bf16)(o[n2][3] * is)};
  }
  __syncthreads();   // all waves' scratch/k/v reads retire; X region -> attn_o

  // ---- attn_o writes for both tiles: o^T layout -> packed 8B row stores ----
  {
    uint32_t row0 = (uint32_t)(mbase * 16 + l15);
    uint32_t row1 = row0 + 16u;
#pragma unroll
    for (int n2 = 0; n2 < 2; ++n2) {
      uint32_t cb = (uint32_t)((h * 32 + n2 * 16 + rloc0) * 2);
      *reinterpret_cast<bf16x4v*>(smem + XOFF + row0 * 384u + swzA(row0, cb)) = p0[n2];
      *reinterpret_cast<bf16x4v*>(smem + XOFF + row1 * 384u + swzA(row1, cb)) = p1[n2];
    }
  }
  __syncthreads();

  // ---- Phase 4: proj, 2x2-tiled with NAMED accumulators (all prior state dead here).
  // wave -> mtile-pair (wave&1), ntile-pair (wave>>1); each A read feeds 2 MFMAs.
  {
    const int mp = wave & 1;
    const int np = wave >> 1;
    const float pb0 = proj_b[(2 * np + 0) * 16 + l15];
    const float pb1 = proj_b[(2 * np + 1) * 16 + l15];
    f32x4 po00 = (f32x4){pb0, pb0, pb0, pb0};
    f32x4 po01 = (f32x4){pb1, pb1, pb1, pb1};
    f32x4 po10 = po00;
    f32x4 po11 = po01;
#pragma unroll
    for (int ks = 0; ks < 6; ++ks) {
      bf16x8 bp0 = *reinterpret_cast<const bf16x8*>(wproj + ((size_t)((2 * np + 0) * 6 + ks) * 64 + lane) * 8);
      bf16x8 bp1 = *reinterpret_cast<const bf16x8*>(wproj + ((size_t)((2 * np + 1) * 6 + ks) * 64 + lane) * 8);
      uint32_t rowa = (uint32_t)((2 * mp + 0) * 16 + l15);
      bf16x8 a0 = *reinterpret_cast<const bf16x8*>(smem + XOFF + rowa * 384u + swzA(rowa, (uint32_t)(ks * 64 + g16)));
      po00 = __builtin_amdgcn_mfma_f32_16x16x32_bf16(a0, bp0, po00, 0, 0, 0);
      po01 = __builtin_amdgcn_mfma_f32_16x16x32_bf16(a0, bp1, po01, 0, 0, 0);
      uint32_t rowb = rowa + 16u;
      bf16x8 a1 = *reinterpret_cast<const bf16x8*>(smem + XOFF + rowb * 384u + swzA(rowb, (uint32_t)(ks * 64 + g16)));
      po10 = __builtin_amdgcn_mfma_f32_16x16x32_bf16(a1, bp0, po10, 0, 0, 0);
      po11 = __builtin_amdgcn_mfma_f32_16x16x32_bf16(a1, bp1, po11, 0, 0, 0);
    }
    float* outg = out + (size_t)b * (TOK * CDIM);
    const int col0 = (2 * np + 0) * 16 + l15;
    const int col1 = (2 * np + 1) * 16 + l15;
    const int rA = (2 * mp + 0) * 16 + rloc0;
    const int rB = (2 * mp + 1) * 16 + rloc0;
#pragma unroll
    for (int r = 0; r < 4; ++r) {
      int rowA = rA + r;
      if (rowA < TOK) {
        outg[rowA * CDIM + col0] = po00[r];
        outg[rowA * CDIM + col1] = po01[r];
      }
      int rowB = rB + r;
      if (rowB < TOK) {
        outg[rowB * CDIM + col0] = po10[r];
        outg[rowB * CDIM + col1] = po11[r];
      }
    }
  }
}

extern "C" void kernel_launch(void* const* d_in, const int* in_sizes, int n_in,
                              void* d_out, int out_size, void* d_ws, size_t ws_size,
                              hipStream_t stream) {
  const float* x = (const float*)d_in[0];
  // d_in[1] = q_global : unused by the reference
  const float* qkv_w = (const float*)d_in[2];
  const float* qkv_b = (const float*)d_in[3];
  const float* proj_w = (const float*)d_in[4];
  const float* proj_b = (const float*)d_in[5];
  const float* rpb = (const float*)d_in[6];

  unsigned short* wqkv = (unsigned short*)d_ws;                 // 36*6*64*8 bf16 = 221184 B
  unsigned short* wproj = wqkv + (size_t)36 * 6 * 64 * 8;       // 12*6*64*8 bf16 = 73728 B
  float* bias_c = (float*)(wproj + (size_t)12 * 6 * 64 * 8);    // 6*4*4*64*4 f32 = 98304 B

  // fused pack: 13824 (wqkv) + 4608 (wproj) + 6144 (bias) = 24576 threads = 96 blocks
  wa_pack_all<<<96, 256, 0, stream>>>(qkv_w, proj_w, rpb, wqkv, wproj, bias_c);

  hipFuncSetAttribute((const void*)wa_main, hipFuncAttributeMaxDynamicSharedMemorySize, (int)SMEM_BYTES);
  wa_main<<<2048, THREADS, SMEM_BYTES, stream>>>(x, qkv_b, proj_b, bias_c, wqkv, wproj, (float*)d_out);
}